// Round 12
// baseline (174.038 us; speedup 1.0000x reference)
//
#include <hip/hip_runtime.h>
#include <math.h>

typedef unsigned int u32;
typedef unsigned short u16;
typedef __attribute__((ext_vector_type(4))) float f32x4;
typedef __attribute__((ext_vector_type(8))) short s16x8;   // 8 bf16 (MFMA A/B frag)

#define BB 2
#define NN 2048
#define DD 1024
#define HH 16
#define ROWS 4096
#define QC 5120            // qkvh cols: q|k|v|hk|hv
#define SCALE 0.125f
#define LOG2E 1.44269504088896f
#define SC2 (SCALE * LOG2E)
#define DEFER_THR 8.0f

#if __has_builtin(__builtin_amdgcn_exp2f)
#define EXP2(x) __builtin_amdgcn_exp2f(x)
#else
#define EXP2(x) __expf((x) * 0.69314718056f)
#endif
#if __has_builtin(__builtin_amdgcn_rcpf)
#define RCP(x) __builtin_amdgcn_rcpf(x)
#else
#define RCP(x) (1.0f / (x))
#endif

__device__ __forceinline__ u16 f2bf(float x) {
    u32 u = __float_as_uint(x);
    return (u16)((u + 0x7FFFu + ((u >> 16) & 1u)) >> 16);
}
__device__ __forceinline__ float bf2f(u16 h) {
    return __uint_as_float(((u32)h) << 16);
}
__device__ __forceinline__ u32 cvtpk(float lo, float hi) {
    u32 r;
    asm("v_cvt_pk_bf16_f32 %0, %1, %2" : "=v"(r) : "v"(lo), "v"(hi));
    return r;
}
__device__ __forceinline__ void gload16(const void* g, void* l) {
    __builtin_amdgcn_global_load_lds(
        (const __attribute__((address_space(1))) unsigned int*)g,
        (__attribute__((address_space(3))) unsigned int*)l, 16, 0, 0);
}

// Transpose a 64x64 V tile into Vt[d][kv] (bf16-pair packed, XOR-swizzled
// chunks). Slot: d*128 + ((s>>2)^(d&7)^(d>>3))*16 + (s&3)*4 — bijective;
// the ^(d>>3) (= sch) term spreads a wave's stores across all 32 banks.
__device__ __forceinline__ void vt_write(char* vbb, uint4 vreg, int srow, int sch)
{
    uint4 oth;
    oth.x = (u32)__shfl_xor((int)vreg.x, 8); oth.y = (u32)__shfl_xor((int)vreg.y, 8);
    oth.z = (u32)__shfl_xor((int)vreg.z, 8); oth.w = (u32)__shfl_xor((int)vreg.w, 8);
    const bool odd = (srow & 1);
    u32 ma = odd ? vreg.z : vreg.x, mb = odd ? vreg.w : vreg.y;
    u32 oa = odd ? oth.z : oth.x,  ob = odd ? oth.w : oth.y;
    u32 ea = odd ? oa : ma, eb = odd ? ob : mb;   // even kv row (2s)
    u32 da = odd ? ma : oa, db = odd ? mb : ob;   // odd  kv row (2s+1)
    u32 pk0 = (ea & 0xffffu) | (da << 16);
    u32 pk1 = (ea >> 16)     | (da & 0xffff0000u);
    u32 pk2 = (eb & 0xffffu) | (db << 16);
    u32 pk3 = (eb >> 16)     | (db & 0xffff0000u);
    const int s = srow >> 1;
    const int d0 = sch * 8 + (odd ? 4 : 0);
    const int sb = (s & 3) * 4;
    *(u32*)(vbb + (d0 + 0) * 128 + ((((s >> 2) ^ ((d0 + 0) & 7) ^ sch) << 4)) + sb) = pk0;
    *(u32*)(vbb + (d0 + 1) * 128 + ((((s >> 2) ^ ((d0 + 1) & 7) ^ sch) << 4)) + sb) = pk1;
    *(u32*)(vbb + (d0 + 2) * 128 + ((((s >> 2) ^ ((d0 + 2) & 7) ^ sch) << 4)) + sb) = pk2;
    *(u32*)(vbb + (d0 + 3) * 128 + ((((s >> 2) ^ ((d0 + 3) & 7) ^ sch) << 4)) + sb) = pk3;
}

// ---------------------------------------------------------------------------
// Fused prep: blocks [0,2048) convert x->bf16; [2048,3584) transpose weights;
// [3584,4096) build rope table. One launch instead of three.
// ---------------------------------------------------------------------------
__global__ __launch_bounds__(256) void prep(const float* __restrict__ x,
                                            const float* __restrict__ wqkv,
                                            const float* __restrict__ whkv,
                                            const float* __restrict__ wout,
                                            uint4* __restrict__ xb,
                                            u16* __restrict__ wT,
                                            float* __restrict__ tab)
{
    __shared__ float T[64][65];
    const int bid = blockIdx.x;
    if (bid < 2048) {
        int t = bid * 256 + threadIdx.x;
        const float4 a = ((const float4*)x)[2 * t];
        const float4 b = ((const float4*)x)[2 * t + 1];
        uint4 o;
        o.x = f2bf(a.x) | ((u32)f2bf(a.y) << 16);
        o.y = f2bf(a.z) | ((u32)f2bf(a.w) << 16);
        o.z = f2bf(b.x) | ((u32)f2bf(b.y) << 16);
        o.w = f2bf(b.z) | ((u32)f2bf(b.w) << 16);
        xb[t] = o;
    } else if (bid < 3584) {
        const int idx = bid - 2048;
        const int bc = idx % 96;
        const int k0 = (idx / 96) * 64;
        const int c0 = bc * 64;
        const float* src; int stride; int csrc;
        if (bc < 48)      { src = wqkv; stride = 3072; csrc = c0; }
        else if (bc < 80) { src = whkv; stride = 2048; csrc = c0 - 3072; }
        else              { src = wout; stride = 1024; csrc = c0 - 5120; }
        const int t = threadIdx.x;
        const int r = t >> 4, c4 = t & 15;
#pragma unroll
        for (int i = 0; i < 4; ++i) {
            int kk = r + 16 * i;
            float4 v = *(const float4*)&src[(size_t)(k0 + kk) * stride + csrc + 4 * c4];
            T[kk][4 * c4 + 0] = v.x; T[kk][4 * c4 + 1] = v.y;
            T[kk][4 * c4 + 2] = v.z; T[kk][4 * c4 + 3] = v.w;
        }
        __syncthreads();
#pragma unroll
        for (int i = 0; i < 4; ++i) {
            int cc = r + 16 * i;
            u32 lo = f2bf(T[4 * c4 + 0][cc]) | ((u32)f2bf(T[4 * c4 + 1][cc]) << 16);
            u32 hi = f2bf(T[4 * c4 + 2][cc]) | ((u32)f2bf(T[4 * c4 + 3][cc]) << 16);
            *(uint2*)&wT[(size_t)(c0 + cc) * 1024 + k0 + 4 * c4] = make_uint2(lo, hi);
        }
    } else {
        int t = (bid - 3584) * 256 + threadIdx.x;
        int n = t >> 6, col = t & 63, i = col & 31;
        float ang = (float)n * exp2f(-(float)i * 0.41524101186092029f);
        tab[t] = (col < 32) ? cosf(ang) : sinf(ang);
    }
}

// ---------------------------------------------------------------------------
// 256x256 bf16 MFMA GEMM, 8-phase-family schedule with provable counted waits.
// C[4096 x 5120] = A[4096 x 1024] @ B^T (wT rows), bf16 out + fused K-RoPE.
// 8 waves (512 thr), BK=64. LDS = 4 half-slots per operand (16KB each,
// slot = (2t+h)&3) = 128KB. Per tile t:
//   1) front-load ALL frags of tile t into regs (24 ds_read_b128),
//      lgkmcnt(0), s_barrier  -> tile t's slots free for overwrite
//   2) stage tile t+2 (8 gloads into slots (2t)&3,(2t+1)&3) interleaved
//      with 4 setprio-wrapped 16-MFMA clusters
//   3) vmcnt(8) (never 0 mid-loop: in-order retirement proves tile t+1's
//      8 loads landed while t+2's 8 stay in flight), s_barrier
// Read swizzle: chunk cl at cl^(row&7) (r6-proven conflict-free), linear
// gload dest + pre-swizzled per-lane source (rule 21).
// ---------------------------------------------------------------------------
__global__ __launch_bounds__(512, 1) void gemm256(
    const u16* __restrict__ A, const u16* __restrict__ B,
    u16* __restrict__ C, const float* __restrict__ tab)
{
    __shared__ u16 As[4][128 * 64];   // 4 x 16KB
    __shared__ u16 Bs[4][128 * 64];   // 4 x 16KB
    const int tid = threadIdx.x;
    const int lane = tid & 63, w = tid >> 6;
    const int g = lane >> 4, c = lane & 15;
    const int wrow = w >> 2, wcol = w & 3;          // 2M x 4N wave grid
    const int rb0 = blockIdx.y * 256, cb0 = blockIdx.x * 256;

    f32x4 acc[8][4];
#pragma unroll
    for (int i = 0; i < 8; ++i)
#pragma unroll
        for (int j = 0; j < 4; ++j) {
            acc[i][j][0] = 0.f; acc[i][j][1] = 0.f; acc[i][j][2] = 0.f; acc[i][j][3] = 0.f;
        }

    const int srow = tid >> 3, sch = tid & 7;       // srow in [0,64)
    const int scol = (sch ^ (srow & 7)) * 8;        // pre-swizzled source chunk
    const u16* asrc = A + (size_t)(rb0 + srow) * 1024 + scol;
    const u16* bsrc = B + (size_t)(cb0 + srow) * 1024 + scol;

    // stage half h (rows h*128..h*128+127) of tile t, both operands: 4 gloads
#define STG(t, h)                                                              \
    {   const int k_ = (t) * 64;                                               \
        const int sl_ = (2 * (t) + (h)) & 3;                                   \
        gload16(asrc + (size_t)((h) * 128) * 1024 + k_,       (char*)As[sl_] + w * 1024);        \
        gload16(asrc + (size_t)((h) * 128 + 64) * 1024 + k_,  (char*)As[sl_] + 8192 + w * 1024); \
        gload16(bsrc + (size_t)((h) * 128) * 1024 + k_,       (char*)Bs[sl_] + w * 1024);        \
        gload16(bsrc + (size_t)((h) * 128 + 64) * 1024 + k_,  (char*)Bs[sl_] + 8192 + w * 1024); \
    }

#define CLUSTER(rlo, kk)                                                       \
    __builtin_amdgcn_s_setprio(1);                                             \
    _Pragma("unroll")                                                          \
    for (int rb = 0; rb < 4; ++rb)                                             \
        _Pragma("unroll")                                                      \
        for (int cb = 0; cb < 4; ++cb)                                         \
            acc[(rlo) + rb][cb] = __builtin_amdgcn_mfma_f32_16x16x32_bf16(     \
                af[(rlo) + rb][kk], bf[cb][kk], acc[(rlo) + rb][cb], 0, 0, 0); \
    __builtin_amdgcn_s_setprio(0);

    // prologue: stage tiles 0 and 1 (16 loads); counted wait drains tile 0
    STG(0, 0); STG(0, 1); STG(1, 0); STG(1, 1);
    asm volatile("s_waitcnt vmcnt(8)" ::: "memory");
    __builtin_amdgcn_s_barrier();

    const int NT = 16;   // K = 1024 / 64
    for (int t = 0; t < NT; ++t) {
        // wave's halves: A half = wrow, B half = wcol>>1
        const char* abase = (const char*)As[(2 * t + wrow) & 3];
        const char* bbase = (const char*)Bs[(2 * t + (wcol >> 1)) & 3];
        s16x8 af[8][2], bf[4][2];
#pragma unroll
        for (int rb = 0; rb < 8; ++rb)
#pragma unroll
            for (int kk = 0; kk < 2; ++kk)
                af[rb][kk] = *(const s16x8*)(abase + (rb * 16 + c) * 128 +
                                             ((((kk << 2) + g) ^ (c & 7)) << 4));
#pragma unroll
        for (int cb = 0; cb < 4; ++cb)
#pragma unroll
            for (int kk = 0; kk < 2; ++kk)
                bf[cb][kk] = *(const s16x8*)(bbase + ((wcol & 1) * 64 + cb * 16 + c) * 128 +
                                             ((((kk << 2) + g) ^ (c & 7)) << 4));
        asm volatile("s_waitcnt lgkmcnt(0)" ::: "memory");
        __builtin_amdgcn_sched_barrier(0);
        __builtin_amdgcn_s_barrier();       // all waves' reads done: slots free
        __builtin_amdgcn_sched_barrier(0);

        if (t + 2 < NT) STG(t + 2, 0);
        CLUSTER(0, 0)
        if (t + 2 < NT) STG(t + 2, 1);
        CLUSTER(0, 1)
        CLUSTER(4, 0)
        CLUSTER(4, 1)

        if (t + 1 < NT) {
            if (t + 2 < NT) asm volatile("s_waitcnt vmcnt(8)" ::: "memory");
            else            asm volatile("s_waitcnt vmcnt(0)" ::: "memory");
            __builtin_amdgcn_s_barrier();   // tile t+1 fully landed for all waves
            __builtin_amdgcn_sched_barrier(0);
        }
    }
#undef STG
#undef CLUSTER

    // ---- epilogue: fused K-RoPE (cols 1024..2047) + bf16 pack + store
    const bool doRope = (cb0 >= 1024 && cb0 < 2048);
#pragma unroll
    for (int rb = 0; rb < 8; ++rb) {
#pragma unroll
        for (int cb = 0; cb < 4; ++cb) {
            if (doRope) {
                const int i = ((wcol * 64 + cb * 16 + c) & 63) >> 1;
#pragma unroll
                for (int e = 0; e < 4; ++e) {
                    int n = (rb0 + wrow * 128 + rb * 16 + g * 4 + e) & (NN - 1);
                    float co = tab[(n << 6) + i], si = tab[(n << 6) + 32 + i];
                    float self = acc[rb][cb][e];
                    float part = __shfl_xor(self, 1);
                    acc[rb][cb][e] = (c & 1) ? fmaf(self, co, part * si)
                                             : fmaf(self, co, -part * si);
                }
            }
            uint2 keep = make_uint2(0, 0);
#pragma unroll
            for (int e = 0; e < 4; ++e) {
                u32 me = f2bf(acc[rb][cb][e]);
                u32 x1 = (u32)__shfl_xor((int)me, 1);
                u32 pair = (c & 1) ? ((x1 & 0xffffu) | (me << 16)) : ((me & 0xffffu) | (x1 << 16));
                u32 x2 = (u32)__shfl_xor((int)pair, 2);
                u32 q0 = (c & 2) ? x2 : pair;
                u32 q1 = (c & 2) ? pair : x2;
                if ((c & 3) == e) keep = make_uint2(q0, q1);
            }
            int row = rb0 + wrow * 128 + rb * 16 + g * 4 + (c & 3);
            int col = cb0 + wcol * 64 + cb * 16 + (c & ~3);
            *(uint2*)(C + (size_t)row * QC + col) = keep;
        }
    }
}

// ---------------------------------------------------------------------------
// 128x128 bf16 MFMA GEMM (r6 structure): BK=64 single-buffer, 32KB LDS,
// conflict-free 8-slot swizzle. f32 out + bias. Output projection only.
// ---------------------------------------------------------------------------
__global__ __launch_bounds__(256, 2) void gemm128(
    const u16* __restrict__ A, int lda,
    const u16* __restrict__ B, int ldb,
    float* __restrict__ C, int ldc,
    const float* __restrict__ bias, int K)
{
    __shared__ u16 As[128 * 64];
    __shared__ u16 Bs[128 * 64];
    const int tid = threadIdx.x;
    const int lane = tid & 63, w = tid >> 6;
    const int g = lane >> 4, c = lane & 15;
    const int wr = w >> 1, wc = w & 1;
    const int rb0 = blockIdx.y * 128, cb0 = blockIdx.x * 128;

    f32x4 acc[4][4];
#pragma unroll
    for (int i = 0; i < 4; ++i)
#pragma unroll
        for (int j = 0; j < 4; ++j) {
            acc[i][j][0] = 0.f; acc[i][j][1] = 0.f; acc[i][j][2] = 0.f; acc[i][j][3] = 0.f;
        }

    const int srow = tid >> 3, sch = tid & 7;
    const int scol = ((sch ^ (srow & 7)) * 8);
    const u16* asrc = A + (size_t)(rb0 + srow) * lda + scol;
    const u16* bsrc = B + (size_t)(cb0 + srow) * ldb + scol;

    for (int k0 = 0; k0 < K; k0 += 64) {
        __syncthreads();
#pragma unroll
        for (int r = 0; r < 4; ++r) {
            gload16(asrc + (size_t)(32 * r) * lda + k0, (char*)As + r * 4096 + w * 1024);
            gload16(bsrc + (size_t)(32 * r) * ldb + k0, (char*)Bs + r * 4096 + w * 1024);
        }
        __syncthreads();
#pragma unroll
        for (int kk = 0; kk < 2; ++kk) {
            s16x8 a[4], b[4];
#pragma unroll
            for (int rb = 0; rb < 4; ++rb) {
                int row = wr * 64 + rb * 16 + c;
                a[rb] = *(const s16x8*)((const char*)As + row * 128 + ((((kk << 2) + g) ^ (row & 7)) << 4));
            }
#pragma unroll
            for (int cb = 0; cb < 4; ++cb) {
                int row = wc * 64 + cb * 16 + c;
                b[cb] = *(const s16x8*)((const char*)Bs + row * 128 + ((((kk << 2) + g) ^ (row & 7)) << 4));
            }
#pragma unroll
            for (int rb = 0; rb < 4; ++rb)
#pragma unroll
                for (int cb = 0; cb < 4; ++cb)
                    acc[rb][cb] = __builtin_amdgcn_mfma_f32_16x16x32_bf16(a[rb], b[cb], acc[rb][cb], 0, 0, 0);
        }
    }
#pragma unroll
    for (int rb = 0; rb < 4; ++rb) {
#pragma unroll
        for (int cb = 0; cb < 4; ++cb) {
            int col = cb0 + wc * 64 + cb * 16 + c;
            float bv = bias ? bias[col] : 0.f;
#pragma unroll
            for (int e = 0; e < 4; ++e) {
                int row = rb0 + wr * 64 + rb * 16 + g * 4 + e;
                C[(size_t)row * ldc + col] = acc[rb][cb][e] + bv;
            }
        }
    }
}

// ---------------------------------------------------------------------------
// Fused lookahead attention (r11 version, frozen).
// ---------------------------------------------------------------------------
__global__ __launch_bounds__(256, 4) void attn(
    const u16* __restrict__ qkvh, const float* __restrict__ alpha,
    const float* __restrict__ tab, u16* __restrict__ aout)
{
    __shared__ u16 Kb[2][64 * 64];   // 8 KB each
    __shared__ u16 Vt[2][64 * 64];   // 8 KB each

    const int bid = blockIdx.x;
    const int j = bid >> 5;
    const int qt = (j < 8) ? (31 - j) : (j < 16) ? (j + 8) : (j < 24) ? (31 - j) : (j - 24);
    const int bh = 4 * (bid & 7) + ((bid >> 3) & 3);    // 4 panels per XCD
    const int b = bh >> 4, h = bh & 15;
    const int tid = threadIdx.x;
    const int w = tid >> 6, lane = tid & 63;
    const int g = lane >> 4, c = lane & 15;
    const u16* base = qkvh + (size_t)b * NN * QC;
    const int q0 = qt * 64;
    const int nrow = q0 + w * 16 + c;        // this lane's q row

    const int srow = tid >> 3, sch = tid & 7;
    const int kscol = (sch ^ ((srow & 3) | (((srow >> 3) & 1) << 2))) * 8;
    const u16* ksrc0 = base + (size_t)srow * QC + 1024 + h * 64 + kscol;
    const u16* vsrc0 = base + (size_t)srow * QC + 2048 + h * 64 + sch * 8;

    const float sig_a = RCP(1.f + EXP2(-alpha[h] * LOG2E));
    const int cbase = (8 * (c >> 2) + (c & 3)) * 128;   // permuted A-row base

    // ---- stage kv tile 0
    gload16(ksrc0, (char*)&Kb[0][0] + w * 1024);
    gload16(ksrc0 + (size_t)32 * QC, (char*)&Kb[0][0] + 4096 + w * 1024);
    uint4 vr0 = *(const uint4*)vsrc0;
    uint4 vr1 = *(const uint4*)(vsrc0 + (size_t)32 * QC);
    vt_write((char*)&Vt[0][0], vr0, srow, sch);
    vt_write((char*)&Vt[0][0], vr1, srow + 32, sch);

    // ---- Q (roped in-register) + HK frags, qhk (log2e-scaled)
    s16x8 qf[2], hf[2];
    float qhL;
    {
        const u16* qp_ = base + (size_t)nrow * QC + h * 64;
        float accq = 0.f;
#pragma unroll
        for (int kk = 0; kk < 2; ++kk) {
            uint4 qv = *(const uint4*)(qp_ + ((kk * 4 + g) * 8));
            uint4 hv = *(const uint4*)(qp_ + 3072 + ((kk * 4 + g) * 8));
            const u16* qe = (const u16*)&qv;
            const u16* he = (const u16*)&hv;
            u32 ow[4];
#pragma unroll
            for (int m2 = 0; m2 < 4; ++m2) {
                int i = (kk * 4 + g) * 4 + m2;
                float co = tab[(nrow << 6) + i], si = tab[(nrow << 6) + 32 + i];
                float x0 = bf2f(qe[2 * m2]), x1 = bf2f(qe[2 * m2 + 1]);
                float r0 = x0 * co - x1 * si;
                float r1 = x1 * co + x0 * si;
                accq += r0 * bf2f(he[2 * m2]) + r1 * bf2f(he[2 * m2 + 1]);
                ow[m2] = (u32)f2bf(r0) | ((u32)f2bf(r1) << 16);
            }
            union { s16x8 v; u32 u[4]; } uq, uh;
            uq.u[0] = ow[0]; uq.u[1] = ow[1]; uq.u[2] = ow[2]; uq.u[3] = ow[3];
            uh.u[0] = hv.x; uh.u[1] = hv.y; uh.u[2] = hv.z; uh.u[3] = hv.w;
            qf[kk] = uq.v; hf[kk] = uh.v;
        }
        accq += __shfl_xor(accq, 16);
        accq += __shfl_xor(accq, 32);
        qhL = accq * SC2;
    }
    __syncthreads();

    f32x4 y[4];
#pragma unroll
    for (int db = 0; db < 4; ++db) { y[db][0] = 0.f; y[db][1] = 0.f; y[db][2] = 0.f; y[db][3] = 0.f; }
    float m = -INFINITY, l = 0.f;

    for (int kt = 0; kt <= qt; ++kt) {
        const int cur = kt & 1;
        const bool haveNext = (kt < qt);
        uint4 vr0n, vr1n;
        if (haveNext) {
            gload16(ksrc0 + (size_t)((kt + 1) * 64) * QC, (char*)&Kb[cur ^ 1][0] + w * 1024);
            gload16(ksrc0 + (size_t)((kt + 1) * 64 + 32) * QC, (char*)&Kb[cur ^ 1][0] + 4096 + w * 1024);
            vr0n = *(const uint4*)(vsrc0 + (size_t)((kt + 1) * 64) * QC);
            vr1n = *(const uint4*)(vsrc0 + (size_t)((kt + 1) * 64 + 32) * QC);
        }

        f32x4 sq[4], sh4[4];
#pragma unroll
        for (int kb = 0; kb < 4; ++kb) {
            sq[kb][0] = 0.f; sq[kb][1] = 0.f; sq[kb][2] = 0.f; sq[kb][3] = 0.f;
            sh4[kb][0] = 0.f; sh4[kb][1] = 0.f; sh4[kb][2] = 0.f; sh4[kb][3] = 0.f;
        }
        const char* kbp = (const char*)&Kb[cur][0] + cbase;
        __builtin_amdgcn_s_setprio(1);
#pragma unroll
        for (int kb = 0; kb < 4; ++kb) {
#pragma unroll
            for (int kk = 0; kk < 2; ++kk) {
                s16x8 kf = *(const s16x8*)(kbp + (kb & 1) * 512 + (kb >> 1) * 4096 +
                                           ((((kk << 2) + g) ^ (c & 7)) << 4));
                sq[kb] = __builtin_amdgcn_mfma_f32_16x16x32_bf16(kf, qf[kk], sq[kb], 0, 0, 0);
                sh4[kb] = __builtin_amdgcn_mfma_f32_16x16x32_bf16(kf, hf[kk], sh4[kb], 0, 0, 0);
            }
        }
        __builtin_amdgcn_s_setprio(0);
        const bool needmask = (kt == qt);
        float mx = -INFINITY;
#pragma unroll
        for (int kb = 0; kb < 4; ++kb) {
#pragma unroll
            for (int e = 0; e < 4; ++e) {
                float zp = sh4[kb][e] * qhL;
                float sil = zp * RCP(1.f + EXP2(-zp));
                float s = fmaf(sq[kb][e], SC2, -sil);
                if (needmask) {
                    int kg = kt * 64 + 32 * (kb >> 1) + 8 * g + 4 * (kb & 1) + e;
                    if (kg > nrow) s = -INFINITY;
                }
                sq[kb][e] = s;
                mx = fmaxf(mx, s);
            }
        }
        mx = fmaxf(mx, __shfl_xor(mx, 16));
        mx = fmaxf(mx, __shfl_xor(mx, 32));
        if (!__all(mx <= m + DEFER_THR)) {
            const float mnew = fmaxf(m, mx);
            const float scl = EXP2(m - mnew);
            m = mnew;
            l *= scl;
#pragma unroll
            for (int db = 0; db < 4; ++db) {
                y[db][0] *= scl; y[db][1] *= scl; y[db][2] *= scl; y[db][3] *= scl;
            }
        }
        float rs = 0.f;
#pragma unroll
        for (int kb = 0; kb < 4; ++kb)
#pragma unroll
            for (int e = 0; e < 4; ++e) {
                float p = EXP2(sq[kb][e] - m);
                sq[kb][e] = p;
                rs += p;
            }
        rs += __shfl_xor(rs, 16);
        rs += __shfl_xor(rs, 32);
        l += rs;
        union { s16x8 v; u32 u[4]; } pa[2];
#pragma unroll
        for (int kk = 0; kk < 2; ++kk) {
            pa[kk].u[0] = cvtpk(sq[2 * kk][0], sq[2 * kk][1]);
            pa[kk].u[1] = cvtpk(sq[2 * kk][2], sq[2 * kk][3]);
            pa[kk].u[2] = cvtpk(sq[2 * kk + 1][0], sq[2 * kk + 1][1]);
            pa[kk].u[3] = cvtpk(sq[2 * kk + 1][2], sq[2 * kk + 1][3]);
        }
        const char* vbp = (const char*)&Vt[cur][0];
        __builtin_amdgcn_s_setprio(1);
#pragma unroll
        for (int kk = 0; kk < 2; ++kk)
#pragma unroll
            for (int db = 0; db < 4; ++db) {
                int row = db * 16 + c;
                int ch = ((kk << 2) + g) ^ (c & 7) ^ (db * 2 + (c >> 3));
                s16x8 vfr = *(const s16x8*)(vbp + row * 128 + (ch << 4));
                y[db] = __builtin_amdgcn_mfma_f32_16x16x32_bf16(vfr, pa[kk].v, y[db], 0, 0, 0);
            }
        __builtin_amdgcn_s_setprio(0);

        if (haveNext) {
            vt_write((char*)&Vt[cur ^ 1][0], vr0n, srow, sch);
            vt_write((char*)&Vt[cur ^ 1][0], vr1n, srow + 32, sch);
        }
        __syncthreads();
    }

    const float inv_l = RCP(l);
    const u16* hvp = base + (size_t)nrow * QC + 4096 + h * 64 + g * 4;
    float hv[4][4];
    float sdot = 0.f;
#pragma unroll
    for (int db = 0; db < 4; ++db) {
        uint2 hw = *(const uint2*)(hvp + db * 16);
        const u16* he = (const u16*)&hw;
#pragma unroll
        for (int e = 0; e < 4; ++e) {
            hv[db][e] = bf2f(he[e]);
            float yn = y[db][e] * inv_l;
            y[db][e] = yn;
            sdot += yn * hv[db][e];
        }
    }
    sdot += __shfl_xor(sdot, 16);
    sdot += __shfl_xor(sdot, 32);
    const float f = sig_a * sdot;
    u16* op = aout + ((size_t)(b * NN + nrow)) * DD + h * 64 + g * 4;
#pragma unroll
    for (int db = 0; db < 4; ++db) {
        u32 o0 = (u32)f2bf(y[db][0] - f * hv[db][0]) | ((u32)f2bf(y[db][1] - f * hv[db][1]) << 16);
        u32 o1 = (u32)f2bf(y[db][2] - f * hv[db][2]) | ((u32)f2bf(y[db][3] - f * hv[db][3]) << 16);
        *(uint2*)(op + db * 16) = make_uint2(o0, o1);
    }
}

// ---------------------------------------------------------------------------
extern "C" void kernel_launch(void* const* d_in, const int* in_sizes, int n_in,
                              void* d_out, int out_size, void* d_ws, size_t ws_size,
                              hipStream_t stream)
{
    const float* x     = (const float*)d_in[0];
    const float* w_qkv = (const float*)d_in[1];
    const float* w_hkv = (const float*)d_in[2];
    const float* w_out = (const float*)d_in[3];
    const float* b_out = (const float*)d_in[4];
    const float* alpha = (const float*)d_in[5];

    char* ws = (char*)d_ws;
    u16*   qkvh = (u16*)ws;                       // 4096x5120 bf16
    uint4* xb   = (uint4*)(ws + 41943040);        // 4096x1024 bf16
    u16*   wT   = (u16*)(ws + 50331648);          // 6144x1024 bf16
    u16*   aout = (u16*)(ws + 62914560);          // 4096x1024 bf16
    float* tab  = (float*)(ws + 71303168);        // 2048x64 f32

    // 0) fused prep: x->bf16, weight transposes, rope table (one launch)
    prep<<<4096, 256, 0, stream>>>(x, w_qkv, w_hkv, w_out, xb, wT, tab);

    // 1) qkvh = x @ [w_qkv | w_hkv]  (+ fused K-RoPE), 256^2 counted-vmcnt
    gemm256<<<dim3(20, 16), 512, 0, stream>>>((const u16*)xb, wT, qkvh, tab);

    // 2) fused attention -> aout  (Q roped in-register inside)
    attn<<<1024, 256, 0, stream>>>(qkvh, alpha, tab, aout);

    // 3) out = aout @ w_out + b_out  (128^2, r6 structure)
    gemm128<<<dim3(8, 32), 256, 0, stream>>>(
        aout, 1024, wT + 5120 * 1024, 1024, (float*)d_out, 1024, b_out, 1024);
}

// Round 13
// 159.023 us; speedup vs baseline: 1.0944x; 1.0944x over previous
//
#include <hip/hip_runtime.h>
#include <math.h>

typedef unsigned int u32;
typedef unsigned short u16;
typedef __attribute__((ext_vector_type(4))) float f32x4;
typedef __attribute__((ext_vector_type(8))) short s16x8;   // 8 bf16 (MFMA A/B frag)

#define BB 2
#define NN 2048
#define DD 1024
#define HH 16
#define ROWS 4096
#define QC 5120            // qkvh cols: q|k|v|hk|hv
#define SCALE 0.125f
#define LOG2E 1.44269504088896f
#define SC2 (SCALE * LOG2E)
#define DEFER_THR 8.0f

#if __has_builtin(__builtin_amdgcn_exp2f)
#define EXP2(x) __builtin_amdgcn_exp2f(x)
#else
#define EXP2(x) __expf((x) * 0.69314718056f)
#endif
#if __has_builtin(__builtin_amdgcn_rcpf)
#define RCP(x) __builtin_amdgcn_rcpf(x)
#else
#define RCP(x) (1.0f / (x))
#endif

__device__ __forceinline__ u16 f2bf(float x) {
    u32 u = __float_as_uint(x);
    return (u16)((u + 0x7FFFu + ((u >> 16) & 1u)) >> 16);
}
__device__ __forceinline__ float bf2f(u16 h) {
    return __uint_as_float(((u32)h) << 16);
}
__device__ __forceinline__ u32 cvtpk(float lo, float hi) {
    u32 r;
    asm("v_cvt_pk_bf16_f32 %0, %1, %2" : "=v"(r) : "v"(lo), "v"(hi));
    return r;
}
__device__ __forceinline__ void gload16(const void* g, void* l) {
    __builtin_amdgcn_global_load_lds(
        (const __attribute__((address_space(1))) unsigned int*)g,
        (__attribute__((address_space(3))) unsigned int*)l, 16, 0, 0);
}

// Transpose a 64x64 V tile into Vt[d][kv] (bf16-pair packed, XOR-swizzled
// chunks). Slot: d*128 + ((s>>2)^(d&7)^(d>>3))*16 + (s&3)*4 — bijective;
// the ^(d>>3) (= sch) term spreads a wave's stores across all 32 banks.
__device__ __forceinline__ void vt_write(char* vbb, uint4 vreg, int srow, int sch)
{
    uint4 oth;
    oth.x = (u32)__shfl_xor((int)vreg.x, 8); oth.y = (u32)__shfl_xor((int)vreg.y, 8);
    oth.z = (u32)__shfl_xor((int)vreg.z, 8); oth.w = (u32)__shfl_xor((int)vreg.w, 8);
    const bool odd = (srow & 1);
    u32 ma = odd ? vreg.z : vreg.x, mb = odd ? vreg.w : vreg.y;
    u32 oa = odd ? oth.z : oth.x,  ob = odd ? oth.w : oth.y;
    u32 ea = odd ? oa : ma, eb = odd ? ob : mb;   // even kv row (2s)
    u32 da = odd ? ma : oa, db = odd ? mb : ob;   // odd  kv row (2s+1)
    u32 pk0 = (ea & 0xffffu) | (da << 16);
    u32 pk1 = (ea >> 16)     | (da & 0xffff0000u);
    u32 pk2 = (eb & 0xffffu) | (db << 16);
    u32 pk3 = (eb >> 16)     | (db & 0xffff0000u);
    const int s = srow >> 1;
    const int d0 = sch * 8 + (odd ? 4 : 0);
    const int sb = (s & 3) * 4;
    *(u32*)(vbb + (d0 + 0) * 128 + ((((s >> 2) ^ ((d0 + 0) & 7) ^ sch) << 4)) + sb) = pk0;
    *(u32*)(vbb + (d0 + 1) * 128 + ((((s >> 2) ^ ((d0 + 1) & 7) ^ sch) << 4)) + sb) = pk1;
    *(u32*)(vbb + (d0 + 2) * 128 + ((((s >> 2) ^ ((d0 + 2) & 7) ^ sch) << 4)) + sb) = pk2;
    *(u32*)(vbb + (d0 + 3) * 128 + ((((s >> 2) ^ ((d0 + 3) & 7) ^ sch) << 4)) + sb) = pk3;
}

// ---------------------------------------------------------------------------
// Fused prep: blocks [0,2048) convert x->bf16; [2048,3584) transpose weights;
// [3584,4096) build rope table. One launch instead of three.
// ---------------------------------------------------------------------------
__global__ __launch_bounds__(256) void prep(const float* __restrict__ x,
                                            const float* __restrict__ wqkv,
                                            const float* __restrict__ whkv,
                                            const float* __restrict__ wout,
                                            uint4* __restrict__ xb,
                                            u16* __restrict__ wT,
                                            float* __restrict__ tab)
{
    __shared__ float T[64][65];
    const int bid = blockIdx.x;
    if (bid < 2048) {
        int t = bid * 256 + threadIdx.x;
        const float4 a = ((const float4*)x)[2 * t];
        const float4 b = ((const float4*)x)[2 * t + 1];
        uint4 o;
        o.x = f2bf(a.x) | ((u32)f2bf(a.y) << 16);
        o.y = f2bf(a.z) | ((u32)f2bf(a.w) << 16);
        o.z = f2bf(b.x) | ((u32)f2bf(b.y) << 16);
        o.w = f2bf(b.z) | ((u32)f2bf(b.w) << 16);
        xb[t] = o;
    } else if (bid < 3584) {
        const int idx = bid - 2048;
        const int bc = idx % 96;
        const int k0 = (idx / 96) * 64;
        const int c0 = bc * 64;
        const float* src; int stride; int csrc;
        if (bc < 48)      { src = wqkv; stride = 3072; csrc = c0; }
        else if (bc < 80) { src = whkv; stride = 2048; csrc = c0 - 3072; }
        else              { src = wout; stride = 1024; csrc = c0 - 5120; }
        const int t = threadIdx.x;
        const int r = t >> 4, c4 = t & 15;
#pragma unroll
        for (int i = 0; i < 4; ++i) {
            int kk = r + 16 * i;
            float4 v = *(const float4*)&src[(size_t)(k0 + kk) * stride + csrc + 4 * c4];
            T[kk][4 * c4 + 0] = v.x; T[kk][4 * c4 + 1] = v.y;
            T[kk][4 * c4 + 2] = v.z; T[kk][4 * c4 + 3] = v.w;
        }
        __syncthreads();
#pragma unroll
        for (int i = 0; i < 4; ++i) {
            int cc = r + 16 * i;
            u32 lo = f2bf(T[4 * c4 + 0][cc]) | ((u32)f2bf(T[4 * c4 + 1][cc]) << 16);
            u32 hi = f2bf(T[4 * c4 + 2][cc]) | ((u32)f2bf(T[4 * c4 + 3][cc]) << 16);
            *(uint2*)&wT[(size_t)(c0 + cc) * 1024 + k0 + 4 * c4] = make_uint2(lo, hi);
        }
    } else {
        int t = (bid - 3584) * 256 + threadIdx.x;
        int n = t >> 6, col = t & 63, i = col & 31;
        float ang = (float)n * exp2f(-(float)i * 0.41524101186092029f);
        tab[t] = (col < 32) ? cosf(ang) : sinf(ang);
    }
}

// ---------------------------------------------------------------------------
// bf16 MFMA GEMM (r6 structure — best measured): C = A @ B^T (B = wT[N][K]).
// 128x128 tile, BK=64 single-buffer, 32KB LDS, 2-barrier loop, global_load_lds
// staging (pre-swizzled source, linear dest), conflict-free 8-slot XOR reads.
// BF16_OUT=1 also applies RoPE to the K region (cols 1024..2047) on fp32 acc.
// ---------------------------------------------------------------------------
template <int BF16_OUT>
__global__ __launch_bounds__(256, 2) void gemm_bf16(
    const u16* __restrict__ A, int lda,
    const u16* __restrict__ B, int ldb,
    void* __restrict__ C, int ldc,
    const float* __restrict__ bias, const float* __restrict__ tab, int K)
{
    __shared__ u16 As[128 * 64];   // 16KB, [row][64k]; chunk cl at cl^(row&7)
    __shared__ u16 Bs[128 * 64];
    const int tid = threadIdx.x;
    const int lane = tid & 63, w = tid >> 6;
    const int g = lane >> 4, c = lane & 15;
    const int wr = w >> 1, wc = w & 1;
    const int rb0 = blockIdx.y * 128, cb0 = blockIdx.x * 128;

    f32x4 acc[4][4];
#pragma unroll
    for (int i = 0; i < 4; ++i)
#pragma unroll
        for (int j = 0; j < 4; ++j) {
            acc[i][j][0] = 0.f; acc[i][j][1] = 0.f; acc[i][j][2] = 0.f; acc[i][j][3] = 0.f;
        }

    const int srow = tid >> 3, sch = tid & 7;
    const int scol = ((sch ^ (srow & 7)) * 8);
    const u16* asrc = A + (size_t)(rb0 + srow) * lda + scol;
    const u16* bsrc = B + (size_t)(cb0 + srow) * ldb + scol;

    for (int k0 = 0; k0 < K; k0 += 64) {
        __syncthreads();
#pragma unroll
        for (int r = 0; r < 4; ++r) {
            gload16(asrc + (size_t)(32 * r) * lda + k0, (char*)As + r * 4096 + w * 1024);
            gload16(bsrc + (size_t)(32 * r) * ldb + k0, (char*)Bs + r * 4096 + w * 1024);
        }
        __syncthreads();
#pragma unroll
        for (int kk = 0; kk < 2; ++kk) {
            s16x8 a[4], b[4];
#pragma unroll
            for (int rb = 0; rb < 4; ++rb) {
                int row = wr * 64 + rb * 16 + c;
                a[rb] = *(const s16x8*)((const char*)As + row * 128 + ((((kk << 2) + g) ^ (row & 7)) << 4));
            }
#pragma unroll
            for (int cb = 0; cb < 4; ++cb) {
                int row = wc * 64 + cb * 16 + c;
                b[cb] = *(const s16x8*)((const char*)Bs + row * 128 + ((((kk << 2) + g) ^ (row & 7)) << 4));
            }
#pragma unroll
            for (int rb = 0; rb < 4; ++rb)
#pragma unroll
                for (int cb = 0; cb < 4; ++cb)
                    acc[rb][cb] = __builtin_amdgcn_mfma_f32_16x16x32_bf16(a[rb], b[cb], acc[rb][cb], 0, 0, 0);
        }
    }

    // ---- fused RoPE on K region (pairs = adjacent cols = adjacent lanes)
    if (BF16_OUT && tab && cb0 >= 1024 && cb0 < 2048) {
#pragma unroll
        for (int rb = 0; rb < 4; ++rb)
#pragma unroll
            for (int cb = 0; cb < 4; ++cb) {
                const int i = ((wc * 64 + cb * 16 + c) & 63) >> 1;
#pragma unroll
                for (int e = 0; e < 4; ++e) {
                    int n = (rb0 + wr * 64 + rb * 16 + g * 4 + e) & (NN - 1);
                    float co = tab[(n << 6) + i], si = tab[(n << 6) + 32 + i];
                    float self = acc[rb][cb][e];
                    float part = __shfl_xor(self, 1);
                    acc[rb][cb][e] = (c & 1) ? fmaf(self, co, part * si)
                                             : fmaf(self, co, -part * si);
                }
            }
    }

#pragma unroll
    for (int rb = 0; rb < 4; ++rb) {
#pragma unroll
        for (int cb = 0; cb < 4; ++cb) {
            if (BF16_OUT) {
                uint2 keep = make_uint2(0, 0);
#pragma unroll
                for (int e = 0; e < 4; ++e) {
                    u32 me = f2bf(acc[rb][cb][e]);
                    u32 x1 = (u32)__shfl_xor((int)me, 1);
                    u32 pair = (c & 1) ? ((x1 & 0xffffu) | (me << 16)) : ((me & 0xffffu) | (x1 << 16));
                    u32 x2 = (u32)__shfl_xor((int)pair, 2);
                    u32 q0 = (c & 2) ? x2 : pair;
                    u32 q1 = (c & 2) ? pair : x2;
                    if ((c & 3) == e) keep = make_uint2(q0, q1);
                }
                int row = rb0 + wr * 64 + rb * 16 + g * 4 + (c & 3);
                int col = cb0 + wc * 64 + cb * 16 + (c & ~3);
                *(uint2*)((u16*)C + (size_t)row * ldc + col) = keep;
            } else {
                int col = cb0 + wc * 64 + cb * 16 + c;
                float bv = bias ? bias[col] : 0.f;
#pragma unroll
                for (int e = 0; e < 4; ++e) {
                    int row = rb0 + wr * 64 + rb * 16 + g * 4 + e;
                    ((float*)C)[(size_t)row * ldc + col] = acc[rb][cb][e] + bv;
                }
            }
        }
    }
}

// ---------------------------------------------------------------------------
// Fused lookahead attention (r11 version) with CU-balanced qt permutation:
// qt(j) chosen so every residue-8 class of j = bid>>5 sums to 62 tile-units
// ({31-k, 16+k, 15-k, k}). Big tiles dispatch first; bh->XCD grouping
// (low 5 bits) unchanged.
// ---------------------------------------------------------------------------
__global__ __launch_bounds__(256, 4) void attn(
    const u16* __restrict__ qkvh, const float* __restrict__ alpha,
    const float* __restrict__ tab, u16* __restrict__ aout)
{
    __shared__ u16 Kb[2][64 * 64];   // 8 KB each
    __shared__ u16 Vt[2][64 * 64];   // 8 KB each

    const int bid = blockIdx.x;
    const int j = bid >> 5;
    const int qt = (j < 8) ? (31 - j) : (j < 16) ? (j + 8) : (j < 24) ? (31 - j) : (j - 24);
    const int bh = 4 * (bid & 7) + ((bid >> 3) & 3);    // 4 panels per XCD
    const int b = bh >> 4, h = bh & 15;
    const int tid = threadIdx.x;
    const int w = tid >> 6, lane = tid & 63;
    const int g = lane >> 4, c = lane & 15;
    const u16* base = qkvh + (size_t)b * NN * QC;
    const int q0 = qt * 64;
    const int nrow = q0 + w * 16 + c;        // this lane's q row

    const int srow = tid >> 3, sch = tid & 7;
    const int kscol = (sch ^ ((srow & 3) | (((srow >> 3) & 1) << 2))) * 8;
    const u16* ksrc0 = base + (size_t)srow * QC + 1024 + h * 64 + kscol;
    const u16* vsrc0 = base + (size_t)srow * QC + 2048 + h * 64 + sch * 8;

    const float sig_a = RCP(1.f + EXP2(-alpha[h] * LOG2E));
    const int cbase = (8 * (c >> 2) + (c & 3)) * 128;   // permuted A-row base

    // ---- stage kv tile 0
    gload16(ksrc0, (char*)&Kb[0][0] + w * 1024);
    gload16(ksrc0 + (size_t)32 * QC, (char*)&Kb[0][0] + 4096 + w * 1024);
    uint4 vr0 = *(const uint4*)vsrc0;
    uint4 vr1 = *(const uint4*)(vsrc0 + (size_t)32 * QC);
    vt_write((char*)&Vt[0][0], vr0, srow, sch);
    vt_write((char*)&Vt[0][0], vr1, srow + 32, sch);

    // ---- Q (roped in-register) + HK frags, qhk (log2e-scaled)
    s16x8 qf[2], hf[2];
    float qhL;
    {
        const u16* qp_ = base + (size_t)nrow * QC + h * 64;
        float accq = 0.f;
#pragma unroll
        for (int kk = 0; kk < 2; ++kk) {
            uint4 qv = *(const uint4*)(qp_ + ((kk * 4 + g) * 8));
            uint4 hv = *(const uint4*)(qp_ + 3072 + ((kk * 4 + g) * 8));
            const u16* qe = (const u16*)&qv;
            const u16* he = (const u16*)&hv;
            u32 ow[4];
#pragma unroll
            for (int m2 = 0; m2 < 4; ++m2) {
                int i = (kk * 4 + g) * 4 + m2;
                float co = tab[(nrow << 6) + i], si = tab[(nrow << 6) + 32 + i];
                float x0 = bf2f(qe[2 * m2]), x1 = bf2f(qe[2 * m2 + 1]);
                float r0 = x0 * co - x1 * si;
                float r1 = x1 * co + x0 * si;
                accq += r0 * bf2f(he[2 * m2]) + r1 * bf2f(he[2 * m2 + 1]);
                ow[m2] = (u32)f2bf(r0) | ((u32)f2bf(r1) << 16);
            }
            union { s16x8 v; u32 u[4]; } uq, uh;
            uq.u[0] = ow[0]; uq.u[1] = ow[1]; uq.u[2] = ow[2]; uq.u[3] = ow[3];
            uh.u[0] = hv.x; uh.u[1] = hv.y; uh.u[2] = hv.z; uh.u[3] = hv.w;
            qf[kk] = uq.v; hf[kk] = uh.v;
        }
        accq += __shfl_xor(accq, 16);
        accq += __shfl_xor(accq, 32);
        qhL = accq * SC2;
    }
    __syncthreads();

    f32x4 y[4];
#pragma unroll
    for (int db = 0; db < 4; ++db) { y[db][0] = 0.f; y[db][1] = 0.f; y[db][2] = 0.f; y[db][3] = 0.f; }
    float m = -INFINITY, l = 0.f;

    for (int kt = 0; kt <= qt; ++kt) {
        const int cur = kt & 1;
        const bool haveNext = (kt < qt);
        uint4 vr0n, vr1n;
        if (haveNext) {
            gload16(ksrc0 + (size_t)((kt + 1) * 64) * QC, (char*)&Kb[cur ^ 1][0] + w * 1024);
            gload16(ksrc0 + (size_t)((kt + 1) * 64 + 32) * QC, (char*)&Kb[cur ^ 1][0] + 4096 + w * 1024);
            vr0n = *(const uint4*)(vsrc0 + (size_t)((kt + 1) * 64) * QC);
            vr1n = *(const uint4*)(vsrc0 + (size_t)((kt + 1) * 64 + 32) * QC);
        }

        f32x4 sq[4], sh4[4];
#pragma unroll
        for (int kb = 0; kb < 4; ++kb) {
            sq[kb][0] = 0.f; sq[kb][1] = 0.f; sq[kb][2] = 0.f; sq[kb][3] = 0.f;
            sh4[kb][0] = 0.f; sh4[kb][1] = 0.f; sh4[kb][2] = 0.f; sh4[kb][3] = 0.f;
        }
        const char* kbp = (const char*)&Kb[cur][0] + cbase;
        __builtin_amdgcn_s_setprio(1);
#pragma unroll
        for (int kb = 0; kb < 4; ++kb) {
#pragma unroll
            for (int kk = 0; kk < 2; ++kk) {
                s16x8 kf = *(const s16x8*)(kbp + (kb & 1) * 512 + (kb >> 1) * 4096 +
                                           ((((kk << 2) + g) ^ (c & 7)) << 4));
                sq[kb] = __builtin_amdgcn_mfma_f32_16x16x32_bf16(kf, qf[kk], sq[kb], 0, 0, 0);
                sh4[kb] = __builtin_amdgcn_mfma_f32_16x16x32_bf16(kf, hf[kk], sh4[kb], 0, 0, 0);
            }
        }
        __builtin_amdgcn_s_setprio(0);
        const bool needmask = (kt == qt);
        float mx = -INFINITY;
#pragma unroll
        for (int kb = 0; kb < 4; ++kb) {
#pragma unroll
            for (int e = 0; e < 4; ++e) {
                float zp = sh4[kb][e] * qhL;
                float sil = zp * RCP(1.f + EXP2(-zp));
                float s = fmaf(sq[kb][e], SC2, -sil);
                if (needmask) {
                    int kg = kt * 64 + 32 * (kb >> 1) + 8 * g + 4 * (kb & 1) + e;
                    if (kg > nrow) s = -INFINITY;
                }
                sq[kb][e] = s;
                mx = fmaxf(mx, s);
            }
        }
        mx = fmaxf(mx, __shfl_xor(mx, 16));
        mx = fmaxf(mx, __shfl_xor(mx, 32));
        if (!__all(mx <= m + DEFER_THR)) {
            const float mnew = fmaxf(m, mx);
            const float scl = EXP2(m - mnew);
            m = mnew;
            l *= scl;
#pragma unroll
            for (int db = 0; db < 4; ++db) {
                y[db][0] *= scl; y[db][1] *= scl; y[db][2] *= scl; y[db][3] *= scl;
            }
        }
        float rs = 0.f;
#pragma unroll
        for (int kb = 0; kb < 4; ++kb)
#pragma unroll
            for (int e = 0; e < 4; ++e) {
                float p = EXP2(sq[kb][e] - m);
                sq[kb][e] = p;
                rs += p;
            }
        rs += __shfl_xor(rs, 16);
        rs += __shfl_xor(rs, 32);
        l += rs;
        union { s16x8 v; u32 u[4]; } pa[2];
#pragma unroll
        for (int kk = 0; kk < 2; ++kk) {
            pa[kk].u[0] = cvtpk(sq[2 * kk][0], sq[2 * kk][1]);
            pa[kk].u[1] = cvtpk(sq[2 * kk][2], sq[2 * kk][3]);
            pa[kk].u[2] = cvtpk(sq[2 * kk + 1][0], sq[2 * kk + 1][1]);
            pa[kk].u[3] = cvtpk(sq[2 * kk + 1][2], sq[2 * kk + 1][3]);
        }
        const char* vbp = (const char*)&Vt[cur][0];
        __builtin_amdgcn_s_setprio(1);
#pragma unroll
        for (int kk = 0; kk < 2; ++kk)
#pragma unroll
            for (int db = 0; db < 4; ++db) {
                int row = db * 16 + c;
                int ch = ((kk << 2) + g) ^ (c & 7) ^ (db * 2 + (c >> 3));
                s16x8 vfr = *(const s16x8*)(vbp + row * 128 + (ch << 4));
                y[db] = __builtin_amdgcn_mfma_f32_16x16x32_bf16(vfr, pa[kk].v, y[db], 0, 0, 0);
            }
        __builtin_amdgcn_s_setprio(0);

        if (haveNext) {
            vt_write((char*)&Vt[cur ^ 1][0], vr0n, srow, sch);
            vt_write((char*)&Vt[cur ^ 1][0], vr1n, srow + 32, sch);
        }
        __syncthreads();
    }

    const float inv_l = RCP(l);
    const u16* hvp = base + (size_t)nrow * QC + 4096 + h * 64 + g * 4;
    float hv[4][4];
    float sdot = 0.f;
#pragma unroll
    for (int db = 0; db < 4; ++db) {
        uint2 hw = *(const uint2*)(hvp + db * 16);
        const u16* he = (const u16*)&hw;
#pragma unroll
        for (int e = 0; e < 4; ++e) {
            hv[db][e] = bf2f(he[e]);
            float yn = y[db][e] * inv_l;
            y[db][e] = yn;
            sdot += yn * hv[db][e];
        }
    }
    sdot += __shfl_xor(sdot, 16);
    sdot += __shfl_xor(sdot, 32);
    const float f = sig_a * sdot;
    u16* op = aout + ((size_t)(b * NN + nrow)) * DD + h * 64 + g * 4;
#pragma unroll
    for (int db = 0; db < 4; ++db) {
        u32 o0 = (u32)f2bf(y[db][0] - f * hv[db][0]) | ((u32)f2bf(y[db][1] - f * hv[db][1]) << 16);
        u32 o1 = (u32)f2bf(y[db][2] - f * hv[db][2]) | ((u32)f2bf(y[db][3] - f * hv[db][3]) << 16);
        *(uint2*)(op + db * 16) = make_uint2(o0, o1);
    }
}

// ---------------------------------------------------------------------------
extern "C" void kernel_launch(void* const* d_in, const int* in_sizes, int n_in,
                              void* d_out, int out_size, void* d_ws, size_t ws_size,
                              hipStream_t stream)
{
    const float* x     = (const float*)d_in[0];
    const float* w_qkv = (const float*)d_in[1];
    const float* w_hkv = (const float*)d_in[2];
    const float* w_out = (const float*)d_in[3];
    const float* b_out = (const float*)d_in[4];
    const float* alpha = (const float*)d_in[5];

    char* ws = (char*)d_ws;
    u16*   qkvh = (u16*)ws;                       // 4096x5120 bf16
    uint4* xb   = (uint4*)(ws + 41943040);        // 4096x1024 bf16
    u16*   wT   = (u16*)(ws + 50331648);          // 6144x1024 bf16
    u16*   aout = (u16*)(ws + 62914560);          // 4096x1024 bf16
    float* tab  = (float*)(ws + 71303168);        // 2048x64 f32

    // 0) fused prep: x->bf16, weight transposes, rope table (one launch)
    prep<<<4096, 256, 0, stream>>>(x, w_qkv, w_hkv, w_out, xb, wT, tab);

    // 1) qkvh = x @ [w_qkv | w_hkv]  (+ fused K-RoPE in epilogue)
    gemm_bf16<1><<<dim3(40, 32), 256, 0, stream>>>(
        (const u16*)xb, 1024, wT, 1024, qkvh, QC, nullptr, tab, 1024);

    // 2) fused attention -> aout  (Q roped in-register inside)
    attn<<<1024, 256, 0, stream>>>(qkvh, alpha, tab, aout);

    // 3) out = aout @ w_out + b_out
    gemm_bf16<0><<<dim3(8, 32), 256, 0, stream>>>(
        aout, 1024, wT + 5120 * 1024, 1024, d_out, 1024, b_out, nullptr, 1024);
}